// Round 1
// 138.749 us; speedup vs baseline: 1.5968x; 1.5968x over previous
//
#include <hip/hip_runtime.h>

typedef __attribute__((ext_vector_type(8))) short short8;
typedef __attribute__((ext_vector_type(4))) float f32x4;
typedef __attribute__((ext_vector_type(4))) unsigned int u32x4;
typedef unsigned short u16;
typedef unsigned int u32;

#define BLOCK 256
#define WPB 4            // waves per block
#define GRID 768         // 3 blocks/CU x 256 CU

// dynamic-LDS byte offsets (all 16B aligned)
#define OFF_W2F 0        // W2 A-frags: 8nt x 4kf x 64lane x 8 bf16 = 32768 B
#define OFF_W3F 32768    // W3 A-frags (row-permuted): 4nt3 x 4kf x 64 x 8 = 16384 B
#define OFF_W1  49152    // 128 x float4 {w0,w1,w2,b1} = 2048 B
#define OFF_B2  51200    // 32 x float4  (b2 grouped per (nt,q))  = 512 B
#define OFF_B3  51712    // 16 x float4  (b3 grouped per (nt3,q)) = 256 B
#define OFF_W4  51968    // 16 x float4  (W4 grouped per (nt3,q)) = 256 B
#define LDS_TOTAL 52224  // -> 3 blocks/CU (3*52224 = 156672 <= 163840)

__device__ __forceinline__ float tanh_fast(float x) {
    float e = __expf(2.0f * x);
    return fmaf(-2.0f, __builtin_amdgcn_rcpf(e + 1.0f), 1.0f);  // exact at +-inf
}
__device__ __forceinline__ u16 f2bf(float f) {   // RNE fp32 -> bf16 (staging only)
    u32 u = __float_as_uint(f);
    return (u16)((u + 0x7fffu + ((u >> 16) & 1u)) >> 16);
}
// gfx950 packed RNE fp32->bf16 pair (no builtin; guide-verified asm recipe)
__device__ __forceinline__ u32 cvt_pk(float lo, float hi) {
    u32 r;
    asm("v_cvt_pk_bf16_f32 %0, %1, %2" : "=v"(r) : "v"(lo), "v"(hi));
    return r;
}
__device__ __forceinline__ short8 as_s8(u32x4 v) {
    union { u32x4 u; short8 s; } t; t.u = v; return t.s;
}
#define MFMA16(acc, a, b) acc = __builtin_amdgcn_mfma_f32_16x16x32_bf16(a, b, acc, 0, 0, 0)

__global__ __launch_bounds__(BLOCK, 3) void pinn_mfma(
    const float* __restrict__ x,
    const float* __restrict__ W1, const float* __restrict__ b1,
    const float* __restrict__ W2, const float* __restrict__ b2,
    const float* __restrict__ W3, const float* __restrict__ b3,
    const float* __restrict__ W4, const float* __restrict__ b4,
    float* __restrict__ out, int N)
{
    extern __shared__ char smem[];
    u16*   w2f = (u16*)(smem + OFF_W2F);
    u16*   w3f = (u16*)(smem + OFF_W3F);
    f32x4* w1v = (f32x4*)(smem + OFF_W1);
    f32x4* b2v = (f32x4*)(smem + OFF_B2);
    f32x4* b3v = (f32x4*)(smem + OFF_B3);
    f32x4* w4v = (f32x4*)(smem + OFF_W4);

    // ---- stage W2 as pre-swizzled A-fragments (coalesced source reads) ----
    // frag value at [nt][kf][lane=(q,e)][j] = W2[32kf+8q+j][16nt+e]
    for (int s = threadIdx.x; s < 128 * 128; s += BLOCK) {
        int k = s >> 7, n = s & 127;
        int kf = k >> 5, qq = (k >> 3) & 3, j = k & 7;
        int nt = n >> 4, ee = n & 15;
        w2f[((nt * 4 + kf) * 64 + qq * 16 + ee) * 8 + j] = f2bf(W2[s]);
    }
    // ---- stage W3 with permuted rows: frag[nt3][kf][(q,e)][j] = W3[phi3][16nt3+e]
    // phi3(32kf+8q+j) = 16*((8kf+j)>>2) + 4q + ((8kf+j)&3); staged via the inverse map
    for (int s = threadIdx.x; s < 128 * 64; s += BLOCK) {
        int fsrc = s >> 6, n = s & 63;
        int A = fsrc >> 4, qq = (fsrc >> 2) & 3, bb = fsrc & 3;
        int i = A * 4 + bb;
        int kf = i >> 3, j = i & 7;
        int nt3 = n >> 4, ee = n & 15;
        w3f[((nt3 * 4 + kf) * 64 + qq * 16 + ee) * 8 + j] = f2bf(W3[s]);
    }
    for (int t = threadIdx.x; t < 128; t += BLOCK)
        w1v[t] = (f32x4){W1[t], W1[128 + t], W1[256 + t], b1[t]};
    for (int t = threadIdx.x; t < 32; t += BLOCK) {
        int f = (t >> 2) * 16 + (t & 3) * 4;
        b2v[t] = (f32x4){b2[f], b2[f + 1], b2[f + 2], b2[f + 3]};
    }
    for (int t = threadIdx.x; t < 16; t += BLOCK) {
        int f = (t >> 2) * 16 + (t & 3) * 4;
        b3v[t] = (f32x4){b3[f], b3[f + 1], b3[f + 2], b3[f + 3]};
        w4v[t] = (f32x4){W4[f], W4[f + 1], W4[f + 2], W4[f + 3]};
    }
    __syncthreads();

    const int lane = threadIdx.x & 63;
    const int wv = threadIdx.x >> 6;
    const int q = lane >> 4;     // k-octet selector
    const int e = lane & 15;     // point index within tile (B-frag col / A-frag row)
    const float b4v = b4[0];

    const u16* w2l = w2f + lane * 8;   // conflict-free linear ds_read_b128 bases
    const u16* w3l = w3f + lane * 8;

    const int ntiles = N >> 4;
    const int gw = blockIdx.x * WPB + wv;
    const int nw = GRID * WPB;

    for (int tile = gw; tile < ntiles; tile += nw) {
        const int gbase = tile << 4;

        // ======= layer 1 (3 -> 128): compute B-fragments directly in registers =======
        // lane (q,e) computes features k = 32kf + 8q + j of point (gbase+e)
        short8 Hv[4], Ha[4], Ht[4], Hc[4];
        {
            const float* xp = x + 3 * (size_t)(gbase + e);
            float x0 = xp[0], x1 = xp[1], x2 = xp[2];
#pragma unroll
            for (int kf = 0; kf < 4; kf++) {
                u32 pv[4], pa[4], pt[4], pc[4];
#pragma unroll
                for (int jp = 0; jp < 4; jp++) {
                    f32x4 wA = w1v[kf * 32 + q * 8 + 2 * jp];       // uniform -> broadcast
                    f32x4 wB = w1v[kf * 32 + q * 8 + 2 * jp + 1];
                    float z0 = fmaf(x0, wA[0], fmaf(x1, wA[1], fmaf(x2, wA[2], wA[3])));
                    float z1 = fmaf(x0, wB[0], fmaf(x1, wB[1], fmaf(x2, wB[2], wB[3])));
                    float h0 = tanh_fast(z0), h1 = tanh_fast(z1);
                    float g0 = fmaf(-h0, h0, 1.0f), g1 = fmaf(-h1, h1, 1.0f);
                    pv[jp] = cvt_pk(h0, h1);
                    pa[jp] = cvt_pk(g0 * wA[0], g1 * wB[0]);            // dz tangent
                    pt[jp] = cvt_pk(g0 * wA[1], g1 * wB[1]);            // dt tangent
                    float c0 = -2.0f * h0 * g0 * wA[0] * wA[0];         // d2z tangent
                    float c1 = -2.0f * h1 * g1 * wB[0] * wB[0];
                    pc[jp] = cvt_pk(c0, c1);
                }
                Hv[kf] = as_s8((u32x4){pv[0], pv[1], pv[2], pv[3]});
                Ha[kf] = as_s8((u32x4){pa[0], pa[1], pa[2], pa[3]});
                Ht[kf] = as_s8((u32x4){pt[0], pt[1], pt[2], pt[3]});
                Hc[kf] = as_s8((u32x4){pc[0], pc[1], pc[2], pc[3]});
            }
        }

        // ======= layer 2 (128 -> 128), swapped MFMA: D[feat][point] =======
        // epilogue writes straight into layer-3 B-fragments (static reg relabeling)
        u32x4 A3v[4], A3a[4], A3t[4], A3c[4];
#pragma unroll
        for (int nt = 0; nt < 8; nt++) {
            f32x4 acv = b2v[nt * 4 + q];                 // bias preloaded as C-init
            f32x4 aca = {0.f, 0.f, 0.f, 0.f};
            f32x4 act = {0.f, 0.f, 0.f, 0.f};
            f32x4 acc_ = {0.f, 0.f, 0.f, 0.f};
#pragma unroll
            for (int kf = 0; kf < 4; kf++) {
                short8 Wk = *(const short8*)(w2l + (nt * 4 + kf) * 512);
                MFMA16(acv, Wk, Hv[kf]);
                MFMA16(aca, Wk, Ha[kf]);
                MFMA16(act, Wk, Ht[kf]);
                MFMA16(acc_, Wk, Hc[kf]);
            }
            float hh[4], na[4], ntv[4], nc[4];
#pragma unroll
            for (int r = 0; r < 4; r++) {
                float h = tanh_fast(acv[r]);
                float g = fmaf(-h, h, 1.0f);
                hh[r] = h;
                na[r] = g * aca[r];
                ntv[r] = g * act[r];
                nc[r] = fmaf(-2.0f * h * g * aca[r], aca[r], g * acc_[r]);
            }
            const int kf3 = nt >> 1, s0 = (nt & 1) * 2;
            A3v[kf3][s0]     = cvt_pk(hh[0], hh[1]);
            A3v[kf3][s0 + 1] = cvt_pk(hh[2], hh[3]);
            A3a[kf3][s0]     = cvt_pk(na[0], na[1]);
            A3a[kf3][s0 + 1] = cvt_pk(na[2], na[3]);
            A3t[kf3][s0]     = cvt_pk(ntv[0], ntv[1]);
            A3t[kf3][s0 + 1] = cvt_pk(ntv[2], ntv[3]);
            A3c[kf3][s0]     = cvt_pk(nc[0], nc[1]);
            A3c[kf3][s0 + 1] = cvt_pk(nc[2], nc[3]);
        }

        // ======= layer 3 (128 -> 64) swapped MFMA + layer 4 folded per-tile =======
        float sT = 0.f, sA = 0.f, sTt = 0.f, sC = 0.f;
#pragma unroll
        for (int nt3 = 0; nt3 < 4; nt3++) {
            f32x4 v3 = b3v[nt3 * 4 + q];
            f32x4 a3 = {0.f, 0.f, 0.f, 0.f};
            f32x4 t3 = {0.f, 0.f, 0.f, 0.f};
            f32x4 c3 = {0.f, 0.f, 0.f, 0.f};
#pragma unroll
            for (int kf = 0; kf < 4; kf++) {
                short8 Wk = *(const short8*)(w3l + (nt3 * 4 + kf) * 512);
                MFMA16(v3, Wk, as_s8(A3v[kf]));
                MFMA16(a3, Wk, as_s8(A3a[kf]));
                MFMA16(t3, Wk, as_s8(A3t[kf]));
                MFMA16(c3, Wk, as_s8(A3c[kf]));
            }
            f32x4 w4q = w4v[nt3 * 4 + q];
#pragma unroll
            for (int r = 0; r < 4; r++) {
                float h = tanh_fast(v3[r]);
                float g = fmaf(-h, h, 1.0f);
                sT  = fmaf(h, w4q[r], sT);
                sA  = fmaf(g * a3[r], w4q[r], sA);
                sTt = fmaf(g * t3[r], w4q[r], sTt);
                float cc = fmaf(-2.0f * h * g * a3[r], a3[r], g * c3[r]);
                sC  = fmaf(cc, w4q[r], sC);
            }
        }

        // reduce across the 4 q-groups (features partitioned over q), point = e
        sT  += __shfl_xor(sT, 16);  sT  += __shfl_xor(sT, 32);
        sA  += __shfl_xor(sA, 16);  sA  += __shfl_xor(sA, 32);
        sTt += __shfl_xor(sTt, 16); sTt += __shfl_xor(sTt, 32);
        sC  += __shfl_xor(sC, 16);  sC  += __shfl_xor(sC, 32);
        if (lane < 16) {
            *(float4*)(out + 4 * (size_t)(gbase + e)) =
                make_float4(sT + b4v, sA, sTt, sC);
        }
    }
}

extern "C" void kernel_launch(void* const* d_in, const int* in_sizes, int n_in,
                              void* d_out, int out_size, void* d_ws, size_t ws_size,
                              hipStream_t stream) {
    const float* x  = (const float*)d_in[0];
    const float* W1 = (const float*)d_in[1];
    const float* b1 = (const float*)d_in[2];
    const float* W2 = (const float*)d_in[3];
    const float* b2 = (const float*)d_in[4];
    const float* W3 = (const float*)d_in[5];
    const float* b3 = (const float*)d_in[6];
    const float* W4 = (const float*)d_in[7];
    const float* b4 = (const float*)d_in[8];
    float* out = (float*)d_out;
    int N = in_sizes[0] / 3;

    (void)hipFuncSetAttribute((const void*)pinn_mfma,
                              hipFuncAttributeMaxDynamicSharedMemorySize, LDS_TOTAL);
    hipLaunchKernelGGL(pinn_mfma, dim3(GRID), dim3(BLOCK), LDS_TOTAL, stream,
                       x, W1, b1, W2, b2, W3, b3, W4, b4, out, N);
}